// Round 8
// baseline (278.395 us; speedup 1.0000x reference)
//
#include <hip/hip_runtime.h>
#include <hip/hip_bf16.h>
#include <stdint.h>

// ---------------- problem constants ----------------
#define BATCH   16384
#define SDIM    128
#define ENCK    10
#define ADIM    32
#define DECK    10
#define HID     2048
#define KSPINE  1280      // SDIM*ENCK

typedef __bf16 bf16x8 __attribute__((ext_vector_type(8)));
typedef float  f32x4  __attribute__((ext_vector_type(4)));
typedef float  f32x16 __attribute__((ext_vector_type(16)));

typedef __attribute__((address_space(1))) const void kGlobalVoid;
typedef __attribute__((address_space(3))) void       kLdsVoid;

__device__ __forceinline__ unsigned short f2b(float f) {
  union { float f; unsigned u; } v; v.f = f;
  unsigned r = v.u + 0x7fffu + ((v.u >> 16) & 1u);   // RNE
  return (unsigned short)(r >> 16);
}

// ---------------- fp32 -> bf16 convert (2 elems/thread) ----------------
__global__ void f2b_kernel(const float* __restrict__ in, unsigned* __restrict__ out, int n2) {
  int i = blockIdx.x * blockDim.x + threadIdx.x;
  if (i >= n2) return;
  float2 v = reinterpret_cast<const float2*>(in)[i];
  out[i] = (unsigned)f2b(v.x) | ((unsigned)f2b(v.y) << 16);
}

// ---------------- encoder: sigmoid((x-mean)/std) -> bf16 spine ----------------
__global__ void encoder_kernel(const float* __restrict__ state,
                               const float* __restrict__ mean,
                               const float* __restrict__ stdv,
                               unsigned* __restrict__ spine) {
  int idx = blockIdx.x * blockDim.x + threadIdx.x;   // b*SDIM + d
  if (idx >= BATCH * SDIM) return;
  int d = idx & (SDIM - 1);
  float x = state[idx];
  float vals[ENCK];
#pragma unroll
  for (int k = 0; k < ENCK; ++k) {
    float z = (x - mean[d * ENCK + k]) / stdv[d * ENCK + k];
    vals[k] = 1.f / (1.f + __expf(-z));
  }
  unsigned* dst = spine + idx * (ENCK / 2);
#pragma unroll
  for (int k = 0; k < ENCK / 2; ++k)
    dst[k] = (unsigned)f2b(vals[2 * k]) | ((unsigned)f2b(vals[2 * k + 1]) << 16);
}

// ---------------- Weff/beff builders: fold grouped-conv into W3 ----------------
__global__ void weff_kernel(const float* __restrict__ W3, const float* __restrict__ Wd,
                            unsigned short* __restrict__ Weff) {
  int idx = blockIdx.x * 256 + threadIdx.x;   // a*2048 + j, 65536 total
  int a = idx >> 11, j = idx & 2047;
  float s = 0.f;
#pragma unroll
  for (int k = 0; k < DECK; ++k)
    s += Wd[a * DECK + k] * W3[(size_t)(a * DECK + k) * HID + j];
  Weff[idx] = f2b(s);
}

__global__ void beff_kernel(const float* __restrict__ b3, const float* __restrict__ Wd,
                            const float* __restrict__ bd, float* __restrict__ beff) {
  int a = threadIdx.x;
  if (a >= ADIM) return;
  float s = bd[a];
#pragma unroll
  for (int k = 0; k < DECK; ++k) s += Wd[a * DECK + k] * b3[a * DECK + k];
  beff[a] = s;
}

// ---------------- 256x256 4-phase bf16 GEMM with mfma_f32_32x32x16 ----------------
// 512 thr = 8 waves (2M x 4N); wave tile 128x64 = 4x2 tiles of 32x32.
// acc[4][2] f32x16 (128 AGPR); frags: afc/afn[4][2] + bfc/bfn[2][2] bf16x8 (96 VGPR).
// 32x32x16 MFMA: 8.07 cy/32k FLOP (vs 4.85/16k for 16x16) -> MFMA floor -17%;
// 4 phases/iter (phase = K-32 slice = 2 ks-subslices of 16) halves barrier count.
// A/B operand layout: lane holds [row=lane&31][k=(lane>>5)*8 + 0..7] (one b128).
// C/D: col=lane&31, row=(reg&3)+8*(reg>>2)+4*(lane>>5)  [guide §3, m74/m101].
// Phase p: {lgkm(0); MFMA16(cur); stage; [vmcnt(4) @P1,P3]; shadow-read p+1; barrier}
// Stage schedule: P0:B1B<-kt1 | P1:A0B<-kt2 | P2:B0B<-kt2 | P3:A1B<-kt3.
// vmcnt(4) at P1 retires {A1B(prevP3), B1B(P0)} keeping A0B in flight;
// at P3 retires {A0B(P1), B0B(P2)} keeping A1B. A gets 2-phase staging lead
// (HBM ~900cy), B 1-phase (L2-hot under M-band XCD mapping). Overwrite-vs-read:
// each buffer's last ds_read is >=1 barrier before its restage phase.

#define A0B 0
#define B0B 32768
#define A1B 65536
#define B1B 98304

#define FENCE asm volatile("" ::: "memory")

// stage one 32KB half-buffer (256 rows x 64 bf16): 4 gload_lds x 512 thr x 16B
#define STAGE4(BASEPTR, R0, LDSB, KT)                                                        \
  _Pragma("unroll")                                                                          \
  for (int g = 0; g < 4; ++g) {                                                              \
    __builtin_amdgcn_global_load_lds(                                                        \
        (kGlobalVoid*)((BASEPTR) + (size_t)((R0) + g * 64 + rs) * K + (KT) + ce),            \
        (kLdsVoid*)(smem + (LDSB) + g * 8192 + t * 16), 16, 0, 0);                           \
  }

// A frags for ks-pair KP (2 slices of 16k): 4 m-tiles x 2
#define DS_AF32(DST, ABASE, KP)                                                              \
  _Pragma("unroll")                                                                          \
  for (int mt = 0; mt < 4; ++mt) {                                                           \
    _Pragma("unroll")                                                                        \
    for (int ksl = 0; ksl < 2; ++ksl) {                                                      \
      DST[mt][ksl] = *reinterpret_cast<const bf16x8*>(                                       \
          smem + (ABASE) + abyte + mt * 4096 + ((((KP) * 64) + ksl * 32 + kh16) ^ swz));     \
    }                                                                                        \
  }

// B frags for ks-pair KP: 2 n-tiles x 2
#define DS_BF32(DST, BBASE, KP)                                                              \
  _Pragma("unroll")                                                                          \
  for (int nt = 0; nt < 2; ++nt) {                                                           \
    _Pragma("unroll")                                                                        \
    for (int ksl = 0; ksl < 2; ++ksl) {                                                      \
      DST[nt][ksl] = *reinterpret_cast<const bf16x8*>(                                       \
          smem + (BBASE) + bbyte + nt * 4096 + ((((KP) * 64) + ksl * 32 + kh16) ^ swz));     \
    }                                                                                        \
  }

#define MFMA16(AF, BF)                                                                       \
  _Pragma("unroll")                                                                          \
  for (int mt = 0; mt < 4; ++mt)                                                             \
    _Pragma("unroll")                                                                        \
    for (int nt = 0; nt < 2; ++nt)                                                           \
      _Pragma("unroll")                                                                      \
      for (int ksl = 0; ksl < 2; ++ksl)                                                      \
        acc[mt][nt] = __builtin_amdgcn_mfma_f32_32x32x16_bf16(                               \
            AF[mt][ksl], BF[nt][ksl], acc[mt][nt], 0, 0, 0);

#define PH(AF_C, BF_C, AF_N, BF_N, SH_A, SH_B, KP, DOVM, STG)                                \
  do {                                                                                       \
    asm volatile("s_waitcnt lgkmcnt(0)" ::: "memory");                                       \
    __builtin_amdgcn_sched_barrier(0);                                                       \
    __builtin_amdgcn_s_setprio(1);                                                           \
    MFMA16(AF_C, BF_C);                                                                      \
    __builtin_amdgcn_s_setprio(0);                                                           \
    STG;                                                                                     \
    if (DOVM) {                                                                              \
      asm volatile("s_waitcnt vmcnt(4)" ::: "memory");                                       \
      __builtin_amdgcn_sched_barrier(0);                                                     \
    }                                                                                        \
    DS_AF32(AF_N, SH_A, KP);                                                                 \
    DS_BF32(BF_N, SH_B, KP);                                                                 \
    FENCE;                                                                                   \
    __builtin_amdgcn_s_barrier();                                                            \
  } while (0)

__global__ __launch_bounds__(512, 2) void gemm256(
    const unsigned short* __restrict__ A,    // [M,K] bf16
    const unsigned short* __restrict__ Bw,   // [2048,K] bf16
    const float* __restrict__ bias,          // [2048]
    unsigned short* __restrict__ Cout,       // [M,2048] bf16
    int K, int NI) {                         // NI = K/128
  __shared__ char smem[131072];

  const int t    = threadIdx.x;
  const int lane = t & 63;
  const int w    = t >> 6;
  const int wr   = w >> 2;      // 0..1
  const int wc   = w & 3;       // 0..3
  const int l31  = lane & 31;
  const int kh16 = (lane >> 5) * 16;            // k-half byte offset
  const int swz  = (lane & 7) << 4;             // row&7 == lane&7 (tile bases %8==0)
  const int abyte = (wr * 128 + l31) * 128;     // A row byte base within half-buffer
  const int bbyte = (wc * 64 + l31) * 128;      // B row byte base
  const int rs   = t >> 3;                      // stage row within 64-row band
  const int ce   = ((t & 7) ^ (rs & 7)) << 3;   // inverse-swizzled col (elements)

  // XCD-aware mapping: XCD owns an M-band x all 8 N-blocks (A fetched once per chip).
  const int bid = blockIdx.x;
  const int xcd = bid & 7, idx = bid >> 3;           // idx in [0,64)
  const int row0 = (xcd * 8 + (idx >> 3)) * 256;
  const int col0 = (idx & 7) * 256;

  f32x16 acc[4][2];
#pragma unroll
  for (int mt = 0; mt < 4; ++mt)
#pragma unroll
    for (int nt = 0; nt < 2; ++nt)
#pragma unroll
      for (int r = 0; r < 16; ++r) acc[mt][nt][r] = 0.f;

  bf16x8 afc[4][2], afn[4][2], bfc[2][2], bfn[2][2];

  // ---- prologue: A0B,B0B <- k0..63; A1B <- k64..127; B1B staged at P0 ----
  STAGE4(A,  row0, A0B, 0);
  STAGE4(Bw, col0, B0B, 0);
  STAGE4(A,  row0, A1B, 64);
  asm volatile("s_waitcnt vmcnt(4)" ::: "memory");   // retire A0B,B0B; A1B in flight
  FENCE;
  __builtin_amdgcn_s_barrier();
  DS_AF32(afc, A0B, 0);
  DS_BF32(bfc, B0B, 0);

  for (int i = 0; i < NI; ++i) {
    int kt0 = i << 7;
    int kt1 = kt0 + 64;
    int kt2 = kt0 + 128; if (kt2 >= K) kt2 -= K;   // wrapped on last iter (data unused)
    int kt3 = kt0 + 192; if (kt3 >= K) kt3 -= K;

    // P0: MFMA buf0 kp0 ; stage B1B<-kt1 ; shadow buf0 kp1
    PH(afc, bfc, afn, bfn, A0B, B0B, 1, false, STAGE4(Bw, col0, B1B, kt1));
    // P1: MFMA buf0 kp1 ; stage A0B<-kt2 ; vm4 ; shadow buf1 kp0
    PH(afn, bfn, afc, bfc, A1B, B1B, 0, true,  STAGE4(A,  row0, A0B, kt2));
    // P2: MFMA buf1 kp0 ; stage B0B<-kt2 ; shadow buf1 kp1
    PH(afc, bfc, afn, bfn, A1B, B1B, 1, false, STAGE4(Bw, col0, B0B, kt2));
    // P3: MFMA buf1 kp1 ; stage A1B<-kt3 ; vm4 ; shadow buf0 kp0 (next-iter data)
    PH(afn, bfn, afc, bfc, A0B, B0B, 0, true,  STAGE4(A,  row0, A1B, kt3));
  }

  // ---- epilogue: bias + relu + bf16 store (32x32 C/D layout) ----
#pragma unroll
  for (int mt = 0; mt < 4; ++mt) {
#pragma unroll
    for (int nt = 0; nt < 2; ++nt) {
      int gc = col0 + wc * 64 + nt * 32 + l31;
      float bv = bias[gc];
#pragma unroll
      for (int r = 0; r < 16; ++r) {
        int gr = row0 + wr * 128 + mt * 32 + (r & 3) + 8 * (r >> 2) + (kh16 >> 2);
        float val = fmaxf(acc[mt][nt][r] + bv, 0.f);
        Cout[(size_t)gr * 2048 + gc] = f2b(val);
      }
    }
  }
}

// ---------------- skinny GEMM3 + tanh: [16384,2048]x[32,2048]^T -> d_out ----------------
__global__ __launch_bounds__(128) void gemm_skinny(
    const unsigned short* __restrict__ A,    // h2 [16384,2048] bf16
    const unsigned short* __restrict__ Bw,   // Weff [32,2048] bf16
    const float* __restrict__ beff,          // [32]
    float* __restrict__ out) {               // [16384,32] fp32
  const int t = threadIdx.x, lane = t & 63, w = t >> 6;
  const int lr = lane & 15, kh = lane >> 4;
  const int row0 = (blockIdx.x * 2 + w) * 16;
  f32x4 acc[2];
  acc[0] = (f32x4){0.f, 0.f, 0.f, 0.f};
  acc[1] = (f32x4){0.f, 0.f, 0.f, 0.f};

  const unsigned short* Arow = A  + (size_t)(row0 + lr) * HID + kh * 8;
  const unsigned short* B0   = Bw + (size_t)(lr) * HID + kh * 8;
  const unsigned short* B1   = Bw + (size_t)(16 + lr) * HID + kh * 8;

#pragma unroll 4
  for (int kt = 0; kt < HID; kt += 32) {
    bf16x8 a  = *reinterpret_cast<const bf16x8*>(Arow + kt);
    bf16x8 b0 = *reinterpret_cast<const bf16x8*>(B0 + kt);
    bf16x8 b1 = *reinterpret_cast<const bf16x8*>(B1 + kt);
    acc[0] = __builtin_amdgcn_mfma_f32_16x16x32_bf16(a, b0, acc[0], 0, 0, 0);
    acc[1] = __builtin_amdgcn_mfma_f32_16x16x32_bf16(a, b1, acc[1], 0, 0, 0);
  }
#pragma unroll
  for (int n = 0; n < 2; ++n)
#pragma unroll
    for (int v = 0; v < 4; ++v) {
      int row = row0 + kh * 4 + v;
      int col = n * 16 + lr;
      out[(size_t)row * ADIM + col] = tanhf(acc[n][v] + beff[col]);
    }
}

// ---------------- launch ----------------
extern "C" void kernel_launch(void* const* d_in, const int* in_sizes, int n_in,
                              void* d_out, int out_size, void* d_ws, size_t ws_size,
                              hipStream_t stream) {
  const float* state    = (const float*)d_in[0];
  const float* mean_enc = (const float*)d_in[1];
  const float* std_enc  = (const float*)d_in[2];
  const float* W1 = (const float*)d_in[3];
  const float* b1 = (const float*)d_in[4];
  const float* W2 = (const float*)d_in[5];
  const float* b2 = (const float*)d_in[6];
  const float* W3 = (const float*)d_in[7];
  const float* b3 = (const float*)d_in[8];
  const float* Wd = (const float*)d_in[9];
  const float* bd = (const float*)d_in[10];

  char* ws = (char*)d_ws;
  unsigned short* W1b   = (unsigned short*)(ws + 0);           //  5,242,880
  unsigned short* W2b   = (unsigned short*)(ws + 5242880);     //  8,388,608
  unsigned short* Weff  = (unsigned short*)(ws + 13631488);    //    131,072
  float*          beff  = (float*)(ws + 13762560);             //        128
  unsigned short* spine = (unsigned short*)(ws + 13762688);    // 41,943,040
  unsigned short* h1    = (unsigned short*)(ws + 55705728);    // 67,108,864
  unsigned short* h2    = (unsigned short*)(ws + 122814592);   // 67,108,864 -> end ~190MB

  // weight preprocessing
  f2b_kernel<<<5120, 256, 0, stream>>>(W1, (unsigned*)W1b, 1310720);
  f2b_kernel<<<8192, 256, 0, stream>>>(W2, (unsigned*)W2b, 2097152);
  weff_kernel<<<256, 256, 0, stream>>>(W3, Wd, Weff);
  beff_kernel<<<1, 64, 0, stream>>>(b3, Wd, bd, beff);

  // encoder
  encoder_kernel<<<(BATCH * SDIM) / 256, 256, 0, stream>>>(state, mean_enc, std_enc, (unsigned*)spine);

  // GEMM chain
  gemm256<<<512, 512, 0, stream>>>(spine, W1b, b1, h1, KSPINE, KSPINE / 128);
  gemm256<<<512, 512, 0, stream>>>(h1,    W2b, b2, h2, HID,    HID / 128);
  gemm_skinny<<<BATCH / 32, 128, 0, stream>>>(h2, Weff, beff, (float*)d_out);
}

// Round 9
// 255.150 us; speedup vs baseline: 1.0911x; 1.0911x over previous
//
#include <hip/hip_runtime.h>
#include <hip/hip_bf16.h>
#include <stdint.h>

// ---------------- problem constants ----------------
#define BATCH   16384
#define SDIM    128
#define ENCK    10
#define ADIM    32
#define DECK    10
#define HID     2048
#define KSPINE  1280      // SDIM*ENCK

typedef __bf16 bf16x8 __attribute__((ext_vector_type(8)));
typedef float  f32x4  __attribute__((ext_vector_type(4)));

typedef __attribute__((address_space(1))) const void kGlobalVoid;
typedef __attribute__((address_space(3))) void       kLdsVoid;

__device__ __forceinline__ unsigned short f2b(float f) {
  union { float f; unsigned u; } v; v.f = f;
  unsigned r = v.u + 0x7fffu + ((v.u >> 16) & 1u);   // RNE
  return (unsigned short)(r >> 16);
}

// ---------------- fp32 -> bf16 convert (2 elems/thread) ----------------
__global__ void f2b_kernel(const float* __restrict__ in, unsigned* __restrict__ out, int n2) {
  int i = blockIdx.x * blockDim.x + threadIdx.x;
  if (i >= n2) return;
  float2 v = reinterpret_cast<const float2*>(in)[i];
  out[i] = (unsigned)f2b(v.x) | ((unsigned)f2b(v.y) << 16);
}

// ---------------- encoder: sigmoid((x-mean)/std) -> bf16 spine ----------------
__global__ void encoder_kernel(const float* __restrict__ state,
                               const float* __restrict__ mean,
                               const float* __restrict__ stdv,
                               unsigned* __restrict__ spine) {
  int idx = blockIdx.x * blockDim.x + threadIdx.x;   // b*SDIM + d
  if (idx >= BATCH * SDIM) return;
  int d = idx & (SDIM - 1);
  float x = state[idx];
  float vals[ENCK];
#pragma unroll
  for (int k = 0; k < ENCK; ++k) {
    float z = (x - mean[d * ENCK + k]) / stdv[d * ENCK + k];
    vals[k] = 1.f / (1.f + __expf(-z));
  }
  unsigned* dst = spine + idx * (ENCK / 2);
#pragma unroll
  for (int k = 0; k < ENCK / 2; ++k)
    dst[k] = (unsigned)f2b(vals[2 * k]) | ((unsigned)f2b(vals[2 * k + 1]) << 16);
}

// ---------------- Weff/beff builders: fold grouped-conv into W3 ----------------
__global__ void weff_kernel(const float* __restrict__ W3, const float* __restrict__ Wd,
                            unsigned short* __restrict__ Weff) {
  int idx = blockIdx.x * 256 + threadIdx.x;   // a*2048 + j, 65536 total
  int a = idx >> 11, j = idx & 2047;
  float s = 0.f;
#pragma unroll
  for (int k = 0; k < DECK; ++k)
    s += Wd[a * DECK + k] * W3[(size_t)(a * DECK + k) * HID + j];
  Weff[idx] = f2b(s);
}

__global__ void beff_kernel(const float* __restrict__ b3, const float* __restrict__ Wd,
                            const float* __restrict__ bd, float* __restrict__ beff) {
  int a = threadIdx.x;
  if (a >= ADIM) return;
  float s = bd[a];
#pragma unroll
  for (int k = 0; k < DECK; ++k) s += Wd[a * DECK + k] * b3[a * DECK + k];
  beff[a] = s;
}

// ---------------- 256x256 8-phase bf16 GEMM, m201-faithful quadrant schedule ----------------
// 512 thr = 8 waves (2M x 4N), wave tile 128x64, 16x16x32 MFMA, acc[8][4].
// Phase body: {ds_reads(cur) ; stage 1 half-tile ; barrier ; lgkm(0) ;
//              setprio(1) ; 16 MFMA ; setprio(0) ; [vmcnt(4) @P4,P8] ; barrier}.
// Quadrants: q = m-half (m-frags 0-3 / 4-7), nh = n-half (n-frags 0-1 / 2-3).
// Per K-64 step: P1: read A-q0(8)+B-n01(4), MFMA q0xn01 | P2: read B-n23(4), q0xn23
//              | P3: read A-q1(8), q1xn23 | P4: no reads, q1xn01 (regs from P1).
// Stage slots (1 half-tile = 128 rows = 2 gload_lds per phase):
//   P1: buf1.A-h0<-kt1  P2: buf1.A-h1<-kt1  P3: buf0.B-h0<-kt2  P4: buf0.B-h1<-kt2
//   P5: buf0.A-h0<-kt2  P6: buf0.A-h1<-kt2  P7: buf1.B-h0<-kt3  P8: buf1.B-h1<-kt3
// Region last-read vs restage (all >=1 barrier apart): buf.A last read P3/P7 ->
// staged P5,P6/P1,P2(next); buf.B last read P2/P6 -> staged P3,P4/P7,P8.
// vmcnt(4) ledger: @P4 FIFO=[pP7,pP8,P1..P4]=12, retire 8 -> buf1 A+B complete;
// @P8 FIFO=[P3..P8]=12, retire 8 -> buf0 complete for next P1. Uniform vmcnt(4).

#define A0B 0
#define B0B 32768
#define A1B 65536
#define B1B 98304

#define FENCE asm volatile("" ::: "memory")

#define STAGE(BASEPTR, R0A, R0B, LDS0, LDS1, KT)                                             \
  __builtin_amdgcn_global_load_lds((kGlobalVoid*)((BASEPTR) + (size_t)((R0A) + rs) * K + (KT) + ce), \
                                   (kLdsVoid*)(smem + (LDS0) + t * 16), 16, 0, 0);           \
  __builtin_amdgcn_global_load_lds((kGlobalVoid*)((BASEPTR) + (size_t)((R0B) + rs) * K + (KT) + ce), \
                                   (kLdsVoid*)(smem + (LDS1) + t * 16), 16, 0, 0);

// A quadrant Q (4 m-frags x 2 ks)
#define DS_A4(DST, ABASE, Q)                                                                 \
  _Pragma("unroll")                                                                          \
  for (int j = 0; j < 4; ++j) {                                                              \
    _Pragma("unroll")                                                                        \
    for (int ks = 0; ks < 2; ++ks) {                                                         \
      int rowl = wr * 128 + (Q) * 64 + j * 16 + lr;                                          \
      DST[j][ks] = *reinterpret_cast<const bf16x8*>(                                         \
          smem + (ABASE) + rowl * 128 + ((((ks) << 6) | (kh << 4)) ^ swz));                  \
    }                                                                                        \
  }

// B n-half NH (2 n-frags x 2 ks)
#define DS_B2(DST, BBASE, NH)                                                                \
  _Pragma("unroll")                                                                          \
  for (int n = 0; n < 2; ++n) {                                                              \
    _Pragma("unroll")                                                                        \
    for (int ks = 0; ks < 2; ++ks) {                                                         \
      int rowl = wc * 64 + ((NH) * 2 + n) * 16 + lr;                                         \
      DST[n][ks] = *reinterpret_cast<const bf16x8*>(                                         \
          smem + (BBASE) + rowl * 128 + ((((ks) << 6) | (kh << 4)) ^ swz));                  \
    }                                                                                        \
  }

// MFMA quadrant: q x nh, 4m x 2n x 2ks = 16
#define MFMAQ(Q, NH, AF, BF)                                                                 \
  _Pragma("unroll")                                                                          \
  for (int j = 0; j < 4; ++j)                                                                \
    _Pragma("unroll")                                                                        \
    for (int n = 0; n < 2; ++n)                                                              \
      _Pragma("unroll")                                                                      \
      for (int ks = 0; ks < 2; ++ks)                                                         \
        acc[(Q) * 4 + j][(NH) * 2 + n] = __builtin_amdgcn_mfma_f32_16x16x32_bf16(            \
            AF[j][ks], BF[n][ks], acc[(Q) * 4 + j][(NH) * 2 + n], 0, 0, 0);

#define BAR __builtin_amdgcn_s_barrier()
#define LGKM0 do { asm volatile("s_waitcnt lgkmcnt(0)" ::: "memory"); \
                   __builtin_amdgcn_sched_barrier(0); } while (0)
#define VM4 do { asm volatile("s_waitcnt vmcnt(4)" ::: "memory"); \
                 __builtin_amdgcn_sched_barrier(0); } while (0)

__global__ __launch_bounds__(512, 2) void gemm256(
    const unsigned short* __restrict__ A,    // [M,K] bf16
    const unsigned short* __restrict__ Bw,   // [2048,K] bf16
    const float* __restrict__ bias,          // [2048]
    unsigned short* __restrict__ Cout,       // [M,2048] bf16
    int K, int NI) {                         // NI = K/128
  __shared__ char smem[131072];

  const int t    = threadIdx.x;
  const int lane = t & 63;
  const int w    = t >> 6;
  const int wr   = w >> 2;      // 0..1
  const int wc   = w & 3;       // 0..3
  const int lr   = lane & 15;
  const int kh   = lane >> 4;   // 0..3
  const int swz  = (lr & 7) << 4;
  const int rs   = t >> 3;                      // stage row within 64-row band
  const int ce   = ((t & 7) ^ (rs & 7)) << 3;   // inverse-swizzled col (elements)

  // XCD-aware mapping: XCD owns an M-band x all 8 N-blocks (A fetched once per chip).
  const int bid = blockIdx.x;
  const int xcd = bid & 7, idx = bid >> 3;           // idx in [0,64)
  const int row0 = (xcd * 8 + (idx >> 3)) * 256;
  const int col0 = (idx & 7) * 256;

  f32x4 acc[8][4];
#pragma unroll
  for (int m = 0; m < 8; ++m)
#pragma unroll
    for (int n = 0; n < 4; ++n)
      acc[m][n] = (f32x4){0.f, 0.f, 0.f, 0.f};

  bf16x8 afq[4][2], bf01[2][2], bf23[2][2];

  // ---- prologue: buf0.A, buf0.B <- kt0 ; buf1.B <- kt1 (left outstanding) ----
  STAGE(A,  row0 + 0,   row0 + 64,  A0B + 0,     A0B + 8192,  0);
  STAGE(A,  row0 + 128, row0 + 192, A0B + 16384, A0B + 24576, 0);
  STAGE(Bw, col0 + 0,   col0 + 64,  B0B + 0,     B0B + 8192,  0);
  STAGE(Bw, col0 + 128, col0 + 192, B0B + 16384, B0B + 24576, 0);
  STAGE(Bw, col0 + 0,   col0 + 64,  B1B + 0,     B1B + 8192,  64);
  STAGE(Bw, col0 + 128, col0 + 192, B1B + 16384, B1B + 24576, 64);
  VM4;                                   // retire buf0's 8 loads; buf1.B (4) in flight
  FENCE;
  BAR;

  for (int i = 0; i < NI; ++i) {
    int kt0 = i << 7;
    int kt1 = kt0 + 64;
    int kt2 = kt0 + 128; if (kt2 >= K) kt2 -= K;   // wrapped on last iter (data unused)
    int kt3 = kt0 + 192; if (kt3 >= K) kt3 -= K;

    // ---- K-step even (buf0) ----
    // P1
    DS_A4(afq, A0B, 0); DS_B2(bf01, B0B, 0);
    STAGE(A,  row0 + 0,   row0 + 64,  A1B + 0,     A1B + 8192,  kt1);
    FENCE; BAR; LGKM0;
    __builtin_amdgcn_s_setprio(1); MFMAQ(0, 0, afq, bf01); __builtin_amdgcn_s_setprio(0);
    FENCE; BAR;
    // P2
    DS_B2(bf23, B0B, 1);
    STAGE(A,  row0 + 128, row0 + 192, A1B + 16384, A1B + 24576, kt1);
    FENCE; BAR; LGKM0;
    __builtin_amdgcn_s_setprio(1); MFMAQ(0, 1, afq, bf23); __builtin_amdgcn_s_setprio(0);
    FENCE; BAR;
    // P3
    DS_A4(afq, A0B, 1);
    STAGE(Bw, col0 + 0,   col0 + 64,  B0B + 0,     B0B + 8192,  kt2);
    FENCE; BAR; LGKM0;
    __builtin_amdgcn_s_setprio(1); MFMAQ(1, 1, afq, bf23); __builtin_amdgcn_s_setprio(0);
    FENCE; BAR;
    // P4 (no reads)
    STAGE(Bw, col0 + 128, col0 + 192, B0B + 16384, B0B + 24576, kt2);
    FENCE; BAR;
    __builtin_amdgcn_s_setprio(1); MFMAQ(1, 0, afq, bf01); __builtin_amdgcn_s_setprio(0);
    VM4;
    FENCE; BAR;

    // ---- K-step odd (buf1) ----
    // P5
    DS_A4(afq, A1B, 0); DS_B2(bf01, B1B, 0);
    STAGE(A,  row0 + 0,   row0 + 64,  A0B + 0,     A0B + 8192,  kt2);
    FENCE; BAR; LGKM0;
    __builtin_amdgcn_s_setprio(1); MFMAQ(0, 0, afq, bf01); __builtin_amdgcn_s_setprio(0);
    FENCE; BAR;
    // P6
    DS_B2(bf23, B1B, 1);
    STAGE(A,  row0 + 128, row0 + 192, A0B + 16384, A0B + 24576, kt2);
    FENCE; BAR; LGKM0;
    __builtin_amdgcn_s_setprio(1); MFMAQ(0, 1, afq, bf23); __builtin_amdgcn_s_setprio(0);
    FENCE; BAR;
    // P7
    DS_A4(afq, A1B, 1);
    STAGE(Bw, col0 + 0,   col0 + 64,  B1B + 0,     B1B + 8192,  kt3);
    FENCE; BAR; LGKM0;
    __builtin_amdgcn_s_setprio(1); MFMAQ(1, 1, afq, bf23); __builtin_amdgcn_s_setprio(0);
    FENCE; BAR;
    // P8 (no reads)
    STAGE(Bw, col0 + 128, col0 + 192, B1B + 16384, B1B + 24576, kt3);
    FENCE; BAR;
    __builtin_amdgcn_s_setprio(1); MFMAQ(1, 0, afq, bf01); __builtin_amdgcn_s_setprio(0);
    VM4;
    FENCE; BAR;
  }
  asm volatile("s_waitcnt vmcnt(0)" ::: "memory");

  // ---- epilogue: bias + relu + bf16 store ----
#pragma unroll
  for (int m = 0; m < 8; ++m) {
    int gr0 = row0 + wr * 128 + m * 16 + kh * 4;
#pragma unroll
    for (int n = 0; n < 4; ++n) {
      int gc = col0 + wc * 64 + n * 16 + lr;
      float bv = bias[gc];
#pragma unroll
      for (int v = 0; v < 4; ++v) {
        float val = fmaxf(acc[m][n][v] + bv, 0.f);
        Cout[(size_t)(gr0 + v) * 2048 + gc] = f2b(val);
      }
    }
  }
}

// ---------------- skinny GEMM3 + tanh: [16384,2048]x[32,2048]^T -> d_out ----------------
__global__ __launch_bounds__(128) void gemm_skinny(
    const unsigned short* __restrict__ A,    // h2 [16384,2048] bf16
    const unsigned short* __restrict__ Bw,   // Weff [32,2048] bf16
    const float* __restrict__ beff,          // [32]
    float* __restrict__ out) {               // [16384,32] fp32
  const int t = threadIdx.x, lane = t & 63, w = t >> 6;
  const int lr = lane & 15, kh = lane >> 4;
  const int row0 = (blockIdx.x * 2 + w) * 16;
  f32x4 acc[2];
  acc[0] = (f32x4){0.f, 0.f, 0.f, 0.f};
  acc[1] = (f32x4){0.f, 0.f, 0.f, 0.f};

  const unsigned short* Arow = A  + (size_t)(row0 + lr) * HID + kh * 8;
  const unsigned short* B0   = Bw + (size_t)(lr) * HID + kh * 8;
  const unsigned short* B1   = Bw + (size_t)(16 + lr) * HID + kh * 8;

#pragma unroll 4
  for (int kt = 0; kt < HID; kt += 32) {
    bf16x8 a  = *reinterpret_cast<const bf16x8*>(Arow + kt);
    bf16x8 b0 = *reinterpret_cast<const bf16x8*>(B0 + kt);
    bf16x8 b1 = *reinterpret_cast<const bf16x8*>(B1 + kt);
    acc[0] = __builtin_amdgcn_mfma_f32_16x16x32_bf16(a, b0, acc[0], 0, 0, 0);
    acc[1] = __builtin_amdgcn_mfma_f32_16x16x32_bf16(a, b1, acc[1], 0, 0, 0);
  }
#pragma unroll
  for (int n = 0; n < 2; ++n)
#pragma unroll
    for (int v = 0; v < 4; ++v) {
      int row = row0 + kh * 4 + v;
      int col = n * 16 + lr;
      out[(size_t)row * ADIM + col] = tanhf(acc[n][v] + beff[col]);
    }
}

// ---------------- launch ----------------
extern "C" void kernel_launch(void* const* d_in, const int* in_sizes, int n_in,
                              void* d_out, int out_size, void* d_ws, size_t ws_size,
                              hipStream_t stream) {
  const float* state    = (const float*)d_in[0];
  const float* mean_enc = (const float*)d_in[1];
  const float* std_enc  = (const float*)d_in[2];
  const float* W1 = (const float*)d_in[3];
  const float* b1 = (const float*)d_in[4];
  const float* W2 = (const float*)d_in[5];
  const float* b2 = (const float*)d_in[6];
  const float* W3 = (const float*)d_in[7];
  const float* b3 = (const float*)d_in[8];
  const float* Wd = (const float*)d_in[9];
  const float* bd = (const float*)d_in[10];

  char* ws = (char*)d_ws;
  unsigned short* W1b   = (unsigned short*)(ws + 0);           //  5,242,880
  unsigned short* W2b   = (unsigned short*)(ws + 5242880);     //  8,388,608
  unsigned short* Weff  = (unsigned short*)(ws + 13631488);    //    131,072
  float*          beff  = (float*)(ws + 13762560);             //        128
  unsigned short* spine = (unsigned short*)(ws + 13762688);    // 41,943,040
  unsigned short* h1    = (unsigned short*)(ws + 55705728);    // 67,108,864
  unsigned short* h2    = (unsigned short*)(ws + 122814592);   // 67,108,864 -> end ~190MB

  // weight preprocessing
  f2b_kernel<<<5120, 256, 0, stream>>>(W1, (unsigned*)W1b, 1310720);
  f2b_kernel<<<8192, 256, 0, stream>>>(W2, (unsigned*)W2b, 2097152);
  weff_kernel<<<256, 256, 0, stream>>>(W3, Wd, Weff);
  beff_kernel<<<1, 64, 0, stream>>>(b3, Wd, bd, beff);

  // encoder
  encoder_kernel<<<(BATCH * SDIM) / 256, 256, 0, stream>>>(state, mean_enc, std_enc, (unsigned*)spine);

  // GEMM chain
  gemm256<<<512, 512, 0, stream>>>(spine, W1b, b1, h1, KSPINE, KSPINE / 128);
  gemm256<<<512, 512, 0, stream>>>(h1,    W2b, b2, h2, HID,    HID / 128);
  gemm_skinny<<<BATCH / 32, 128, 0, stream>>>(h2, Weff, beff, (float*)d_out);
}